// Round 10
// baseline (140.803 us; speedup 1.0000x reference)
//
#include <hip/hip_runtime.h>
#include <hip/hip_bf16.h>

#define Bn 4
#define Sn 2048
#define Hn 768
#define NHn 12
#define Mn (Bn*Sn)
#define QKVN 2304

typedef unsigned short u16;
typedef unsigned int u32;
typedef __attribute__((ext_vector_type(8))) short short8;
typedef __attribute__((ext_vector_type(4))) float f32x4;

typedef __attribute__((address_space(1))) const u32 g_u32;
typedef __attribute__((address_space(3))) u32 l_u32;

__device__ __forceinline__ void gll16(const void* g, void* l) {
    __builtin_amdgcn_global_load_lds((g_u32*)g, (l_u32*)l, 16, 0, 0);
}

__device__ __forceinline__ u16 f2bf(float f) {
    u32 x = __float_as_uint(f);
    x += 0x7fffu + ((x >> 16) & 1u);   // round-to-nearest-even
    return (u16)(x >> 16);
}
__device__ __forceinline__ float bf2f(u16 u) {
    return __uint_as_float(((u32)u) << 16);
}

// ------- fused: RoPE cos/sin table + fp32->bf16 casts (one launch) --------
__global__ __launch_bounds__(256) void prep_k(const float* __restrict__ hs,
                                              const float* __restrict__ wqkv,
                                              const float* __restrict__ wo,
                                              const int* __restrict__ pos_ids,
                                              u16* __restrict__ hs_b,
                                              u16* __restrict__ wqkv_b,
                                              u16* __restrict__ wo_b,
                                              float2* __restrict__ tab) {
    int i = blockIdx.x * 256 + threadIdx.x;
    if (i < 262144) {   // RoPE table: Mn*32 entries
        int d2 = i & 31, row = i >> 5;
        float invf = exp2f((float)d2 * -0.4152410119f);   // 10000^(-d2/32)
        float fr = (float)pos_ids[row] * invf;
        float sn, cs;
        sincosf(fr, &sn, &cs);
        tab[i] = make_float2(cs, sn);
        return;
    }
    i -= 262144;
    const float* s; u16* d; int off;
    if (i < 1572864)      { s = hs;   d = hs_b;   off = i; }
    else if (i < 2015232) { s = wqkv; d = wqkv_b; off = i - 1572864; }
    else if (i < 2162688) { s = wo;   d = wo_b;   off = i - 2015232; }
    else return;
    float4 v = ((const float4*)s)[off];
    ushort4 o;
    o.x = f2bf(v.x); o.y = f2bf(v.y); o.z = f2bf(v.z); o.w = f2bf(v.w);
    ((ushort4*)d)[off] = o;
}

// ---------------- bf16 GEMM: C[M][N] = A[M][K] * B[N][K]^T ----------------
// Round-3 structure (best measured gemm1: 44.3 us): BMxBN tile, BK=64,
// 4 waves (2x2), per-wave (BM/2)x(BN/2) of 16x16 frags, single-buffered LDS,
// 2 barriers per K-step. LDS rows 128B = 8x16B granules; XOR swizzle
// slot^(row&7) -> exact 2-way bank aliasing (free; measured 0 conflicts).
// Inverse swizzle applied to the global source column (gll dest linear).
// NEW (round 10): __launch_bounds__(256, 5) -> 5 waves/EU allows 5 blocks/CU
// residency (5 x 32KB = 160KB = full LDS). gemm1's 1152-block grid then fits
// ONE dispatch round (capacity 1280) -- eliminates the 2.25-round tail that
// capped every prior 128^2 variant at ~44-52 us.
// ROPE: fused rotary via table (wave spans exactly one 64-col head block).
template <int BM, int BN, typename OUT, bool ROPE>
__global__ __launch_bounds__(256, 5) void gemm_bt(const u16* __restrict__ A,
                                                  const u16* __restrict__ Bw,
                                                  OUT* __restrict__ C,
                                                  const float2* __restrict__ tab,
                                                  int N, int K) {
    constexpr int WM = BM / 2, WN = BN / 2;
    constexpr int MR = WM / 16, NR = WN / 16;
    static_assert(!ROPE || NR == 4, "ROPE fusion assumes wave spans one 64-head");
    __shared__ __align__(16) u16 As[BM * 64];
    __shared__ __align__(16) u16 Bs[BN * 64];
    const int t = threadIdx.x;
    const int wid = t >> 6, lane = t & 63;
    const int wr = wid >> 1, wc = wid & 1;
    const long m0 = (long)blockIdx.x * BM;
    const long n0 = (long)blockIdx.y * BN;
    const int lr = lane & 15, g = lane >> 4;

    f32x4 acc[MR][NR] = {};

    for (int kt = 0; kt < K; kt += 64) {
        #pragma unroll
        for (int ss = 0; ss < BM / 32; ++ss) {
            int s = t + ss * 256;
            int row = s >> 3, gg = s & 7;
            int col8 = (gg ^ (row & 7)) * 8;   // inverse-swizzled source col
            gll16(A + (m0 + row) * K + kt + col8, (char*)As + s * 16);
        }
        #pragma unroll
        for (int ss = 0; ss < BN / 32; ++ss) {
            int s = t + ss * 256;
            int row = s >> 3, gg = s & 7;
            int col8 = (gg ^ (row & 7)) * 8;
            gll16(Bw + (n0 + row) * K + kt + col8, (char*)Bs + s * 16);
        }
        __syncthreads();
        #pragma unroll
        for (int kk2 = 0; kk2 < 2; ++kk2) {
            const int slot = kk2 * 4 + g;
            short8 bfr[NR];
            #pragma unroll
            for (int nt = 0; nt < NR; ++nt) {
                int row = wc * WN + nt * 16 + lr;
                bfr[nt] = *(const short8*)((const char*)Bs + row * 128 +
                                           ((slot ^ (row & 7)) << 4));
            }
            #pragma unroll
            for (int mt = 0; mt < MR; ++mt) {
                int row = wr * WM + mt * 16 + lr;
                short8 af = *(const short8*)((const char*)As + row * 128 +
                                             ((slot ^ (row & 7)) << 4));
                #pragma unroll
                for (int nt = 0; nt < NR; ++nt)
                    acc[mt][nt] = __builtin_amdgcn_mfma_f32_16x16x32_bf16(
                        af, bfr[nt], acc[mt][nt], 0, 0, 0);
            }
        }
        __syncthreads();
    }

    // ---- epilogue: fused RoPE via table (wave spans exactly one head) ----
    if constexpr (ROPE) {
        if ((n0 + wc * WN) < 1536) {
            #pragma unroll
            for (int mt = 0; mt < MR; ++mt)
                #pragma unroll
                for (int r = 0; r < 4; ++r) {
                    long row = m0 + wr * WM + mt * 16 + g * 4 + r;
                    const float2* tr = tab + row * 32;
                    #pragma unroll
                    for (int ntp = 0; ntp < 2; ++ntp) {
                        float2 cssn = tr[ntp * 16 + lr];
                        float x1 = acc[mt][ntp][r], x2 = acc[mt][ntp + 2][r];
                        acc[mt][ntp][r]     = x1 * cssn.x - x2 * cssn.y;
                        acc[mt][ntp + 2][r] = x2 * cssn.x + x1 * cssn.y;
                    }
                }
        }
    }

    #pragma unroll
    for (int mt = 0; mt < MR; ++mt)
        #pragma unroll
        for (int nt = 0; nt < NR; ++nt)
            #pragma unroll
            for (int r = 0; r < 4; ++r) {
                long row = m0 + wr * WM + mt * 16 + g * 4 + r;
                long col = n0 + wc * WN + nt * 16 + lr;
                float v = acc[mt][nt][r];
                if constexpr (sizeof(OUT) == 2) C[row * N + col] = (OUT)f2bf(v);
                else                            C[row * N + col] = v;
            }
}

// ---------------- windowed attention ----------------
__global__ __launch_bounds__(256) void attn_k(const u16* __restrict__ qkv,
                                              u16* __restrict__ outb) {
    const int qt = blockIdx.x, bh = blockIdx.y;
    const int b = bh / NHn, h = bh % NHn;
    const int q0 = qt * 64, kv0 = q0 - 64;
    const int t = threadIdx.x, wid = t >> 6, lane = t & 63;
    const int lr = lane & 15, g = lane >> 4;

    __shared__ __align__(16) char smem[58368];
    u16* Qs = (u16*)smem;                // [64][64] swizzled, 8192 B
    u16* Ks = (u16*)(smem + 8192);       // [192][64] swizzled, 24576 B
    u16* Vt = (u16*)(smem + 32768);      // [64][200] transposed V, 25600 B

    const size_t rowbase = (size_t)b * Sn;

    #pragma unroll
    for (int ss = 0; ss < 2; ++ss) {
        int s = t + ss * 256;
        int row = s >> 3, gg = s & 7;
        int col8 = (gg ^ (row & 7)) * 8;
        gll16(qkv + (rowbase + q0 + row) * QKVN + h * 64 + col8, (char*)Qs + s * 16);
    }
    #pragma unroll
    for (int ss = 0; ss < 6; ++ss) {
        int s = t + ss * 256;
        int row = s >> 3, gg = s & 7;
        int kk = kv0 + row;
        kk = kk < 0 ? 0 : (kk > Sn - 1 ? Sn - 1 : kk);
        int col8 = (gg ^ (row & 7)) * 8;
        gll16(qkv + (rowbase + kk) * QKVN + 768 + h * 64 + col8, (char*)Ks + s * 16);
    }
    #pragma unroll
    for (int ss = 0; ss < 6; ++ss) {
        int s = t + ss * 256;
        int krow = s >> 3, gg = s & 7;
        int kk = kv0 + krow;
        kk = kk < 0 ? 0 : (kk > Sn - 1 ? Sn - 1 : kk);
        short8 v = *(const short8*)(qkv + (rowbase + kk) * QKVN + 1536 + h * 64 + gg * 8);
        #pragma unroll
        for (int j = 0; j < 8; ++j) Vt[(gg * 8 + j) * 200 + krow] = (u16)v[j];
    }
    __syncthreads();

    f32x4 sacc[12] = {};
    #pragma unroll
    for (int kk2 = 0; kk2 < 2; ++kk2) {
        int qrow = wid * 16 + lr;
        int slot = kk2 * 4 + g;
        short8 qf = *(const short8*)((const char*)Qs + qrow * 128 + ((slot ^ (qrow & 7)) << 4));
        #pragma unroll
        for (int tl = 0; tl < 12; ++tl) {
            int krow = tl * 16 + lr;
            short8 kf = *(const short8*)((const char*)Ks + krow * 128 + ((slot ^ (krow & 7)) << 4));
            sacc[tl] = __builtin_amdgcn_mfma_f32_16x16x32_bf16(qf, kf, sacc[tl], 0, 0, 0);
        }
    }

    float p[12][4];
    float lsum[4];
    #pragma unroll
    for (int r = 0; r < 4; ++r) {
        int qq = q0 + wid * 16 + g * 4 + r;
        float mx = -3.0e38f;
        #pragma unroll
        for (int tl = 0; tl < 12; ++tl) {
            int kq = kv0 + tl * 16 + lr;
            float sc = sacc[tl][r] * 0.125f;
            int dqk = qq - kq;
            bool valid = (kq >= 0) && (kq < Sn) && (dqk <= 64) && (dqk >= -64);
            sc = valid ? sc : -3.0e38f;
            p[tl][r] = sc;
            mx = fmaxf(mx, sc);
        }
        #pragma unroll
        for (int mk = 1; mk < 16; mk <<= 1) mx = fmaxf(mx, __shfl_xor(mx, mk, 16));
        float sum = 0.f;
        #pragma unroll
        for (int tl = 0; tl < 12; ++tl) {
            float e = __expf(p[tl][r] - mx);
            p[tl][r] = e;
            sum += e;
        }
        #pragma unroll
        for (int mk = 1; mk < 16; mk <<= 1) sum += __shfl_xor(sum, mk, 16);
        lsum[r] = sum;
    }

    __syncthreads();

    u16* Pw = (u16*)(smem + wid * 6400);
    #pragma unroll
    for (int tl = 0; tl < 12; ++tl)
        #pragma unroll
        for (int r = 0; r < 4; ++r)
            Pw[(g * 4 + r) * 200 + tl * 16 + lr] = f2bf(p[tl][r]);

    f32x4 oacc[4] = {};
    #pragma unroll
    for (int ks = 0; ks < 6; ++ks) {
        short8 pf = *(const short8*)((const char*)Pw + lr * 400 + (ks * 32 + g * 8) * 2);
        #pragma unroll
        for (int dt = 0; dt < 4; ++dt) {
            short8 vf = *(const short8*)((const char*)Vt + (dt * 16 + lr) * 400 + (ks * 32 + g * 8) * 2);
            oacc[dt] = __builtin_amdgcn_mfma_f32_16x16x32_bf16(pf, vf, oacc[dt], 0, 0, 0);
        }
    }

    #pragma unroll
    for (int dt = 0; dt < 4; ++dt)
        #pragma unroll
        for (int r = 0; r < 4; ++r) {
            int row = q0 + wid * 16 + g * 4 + r;
            float v = oacc[dt][r] / lsum[r];
            outb[(rowbase + row) * Hn + h * 64 + dt * 16 + lr] = f2bf(v);
        }
}

extern "C" void kernel_launch(void* const* d_in, const int* in_sizes, int n_in,
                              void* d_out, int out_size, void* d_ws, size_t ws_size,
                              hipStream_t stream) {
    const float* hs   = (const float*)d_in[0];
    const int*   pos  = (const int*)d_in[1];
    const float* wqkv = (const float*)d_in[2];
    const float* wo   = (const float*)d_in[3];
    float* out = (float*)d_out;
    char* ws = (char*)d_ws;

    u16* hs_b   = (u16*)(ws);              // 8192*768*2   = 12,582,912
    u16* wqkv_b = (u16*)(ws + 12582912);   // 2304*768*2   =  3,538,944
    u16* wo_b   = (u16*)(ws + 16121856);   // 768*768*2    =  1,179,648
    u16* qkv    = (u16*)(ws + 17301504);   // 8192*2304*2  = 37,748,736
    u16* attn   = (u16*)(ws + 55050240);   // 8192*768*2   = 12,582,912
    float2* tab = (float2*)(ws + 55050240);   // 2MB, dead before attn_k writes

    prep_k<<<9472, 256, 0, stream>>>(hs, wqkv, wo, pos, hs_b, wqkv_b, wo_b, tab);

    // qkv = hs @ Wqkv^T with fused RoPE; 1152 blocks @ 5 blocks/CU -> 1 round
    gemm_bt<128, 128, u16, true><<<dim3(64, 18), 256, 0, stream>>>(
        hs_b, wqkv_b, qkv, tab, 2304, 768);

    attn_k<<<dim3(32, 48), 256, 0, stream>>>(qkv, attn);

    // out = attn @ Wo^T (fp32 out); 768 blocks @ 5 blocks/CU -> 1 round
    gemm_bt<128, 64, float, false><<<dim3(64, 12), 256, 0, stream>>>(
        attn, wo_b, out, nullptr, 768, 768);
}

// Round 11
// 104.626 us; speedup vs baseline: 1.3458x; 1.3458x over previous
//
#include <hip/hip_runtime.h>
#include <hip/hip_bf16.h>

#define Bn 4
#define Sn 2048
#define Hn 768
#define NHn 12
#define Mn (Bn*Sn)
#define QKVN 2304

typedef unsigned short u16;
typedef unsigned int u32;
typedef __attribute__((ext_vector_type(8))) short short8;
typedef __attribute__((ext_vector_type(4))) float f32x4;

typedef __attribute__((address_space(1))) const u32 g_u32;
typedef __attribute__((address_space(3))) u32 l_u32;

__device__ __forceinline__ void gll16(const void* g, void* l) {
    __builtin_amdgcn_global_load_lds((g_u32*)g, (l_u32*)l, 16, 0, 0);
}

__device__ __forceinline__ u16 f2bf(float f) {
    u32 x = __float_as_uint(f);
    x += 0x7fffu + ((x >> 16) & 1u);   // round-to-nearest-even
    return (u16)(x >> 16);
}
__device__ __forceinline__ float bf2f(u16 u) {
    return __uint_as_float(((u32)u) << 16);
}

// KWAIT(N): K-tile gate. Counted vmcnt (never 0 in steady state) keeps
// prefetch loads in flight ACROSS the barrier (T4); sched_barrier(0) stops
// the compiler hoisting the following ds_reads above the gate.
#define KWAIT(N) do { \
    asm volatile("s_waitcnt vmcnt(" #N ")" ::: "memory"); \
    __builtin_amdgcn_s_barrier(); \
    __builtin_amdgcn_sched_barrier(0); \
} while (0)

// ------- fused: RoPE cos/sin table + fp32->bf16 casts (one launch) --------
__global__ __launch_bounds__(256) void prep_k(const float* __restrict__ hs,
                                              const float* __restrict__ wqkv,
                                              const float* __restrict__ wo,
                                              const int* __restrict__ pos_ids,
                                              u16* __restrict__ hs_b,
                                              u16* __restrict__ wqkv_b,
                                              u16* __restrict__ wo_b,
                                              float2* __restrict__ tab) {
    int i = blockIdx.x * 256 + threadIdx.x;
    if (i < 262144) {   // RoPE table: Mn*32 entries
        int d2 = i & 31, row = i >> 5;
        float invf = exp2f((float)d2 * -0.4152410119f);   // 10000^(-d2/32)
        float fr = (float)pos_ids[row] * invf;
        float sn, cs;
        sincosf(fr, &sn, &cs);
        tab[i] = make_float2(cs, sn);
        return;
    }
    i -= 262144;
    const float* s; u16* d; int off;
    if (i < 1572864)      { s = hs;   d = hs_b;   off = i; }
    else if (i < 2015232) { s = wqkv; d = wqkv_b; off = i - 1572864; }
    else if (i < 2162688) { s = wo;   d = wo_b;   off = i - 2015232; }
    else return;
    float4 v = ((const float4*)s)[off];
    ushort4 o;
    o.x = f2bf(v.x); o.y = f2bf(v.y); o.z = f2bf(v.z); o.w = f2bf(v.w);
    ((ushort4*)d)[off] = o;
}

// ====== 256x256 8-wave pipelined QKV GEMM (LDS-intensity redesign) =========
// Why: 64x64-wave kernels do 32 FLOP per LDS-read-byte; CU needs 4061
// FLOP/cy vs 128 B/cy LDS -> breakeven 31.7 FLOP/B. Reads alone saturate
// LDS; staging writes push past it -> structural ~33% MfmaUtil cap seen in
// rounds 1-9. Here each wave owns 128x64 = 8x4 frags: 12 KB reads / 32
// MFMAs = 42.7 FLOP/B. Per-CU per K32: MFMA 1033 cy vs LDS 1000 cy.
// Schedule: r9's race-verified 3-slot BK=32 single-gate counted-vmcnt
// pipeline (KWAIT(4); 12 ds_read; stage it+2 into slot(it-1); 32 MFMA).
// Swizzle: rows 64B = 4x16B granules, gran = g ^ ((row>>1)&3) -- enumerated
// exact 2-way bank aliasing (free), measured 0 conflicts in r8/r9.
// 1 block/CU (96 KB LDS, ~190 VGPR @ launch_bounds(512,2)); grid 288.
__global__ __launch_bounds__(512, 2) void gemm256(const u16* __restrict__ A,
                                                  const u16* __restrict__ Bw,
                                                  u16* __restrict__ C,
                                                  const float2* __restrict__ tab) {
    constexpr int K = 768, N = QKVN, NT = K / 32;   // 24 K-tiles
    __shared__ __align__(16) u16 As[3][256 * 32];   // 3 x 16 KB
    __shared__ __align__(16) u16 Bs[3][256 * 32];   // 3 x 16 KB (96 KB)
    const int t = threadIdx.x;
    const int wid = t >> 6, lane = t & 63;
    const int wm = wid >> 2, wn = wid & 3;          // 2M x 4N waves
    const int lr = lane & 15, g = lane >> 4;

    // m-fastest linear grid: consecutive blocks share the B-panel (N-tile)
    const long m0 = (long)(blockIdx.x & 31) * 256;
    const long n0 = (long)(blockIdx.x >> 5) * 256;

    f32x4 acc[8][4] = {};

    // stage one K-tile: A 2 + B 2 gll16 per thread (4 loads in flight)
    auto stage = [&](int slot, int kt) {
        #pragma unroll
        for (int j = 0; j < 2; ++j) {
            int idx = t + j * 512;               // 0..1023
            int row = idx >> 2, gg = idx & 3;
            int col8 = (gg ^ ((row >> 1) & 3)) * 8;   // inverse swizzle
            gll16(A + (m0 + row) * K + kt * 32 + col8, (char*)As[slot] + idx * 16);
        }
        #pragma unroll
        for (int j = 0; j < 2; ++j) {
            int idx = t + j * 512;
            int row = idx >> 2, gg = idx & 3;
            int col8 = (gg ^ ((row >> 1) & 3)) * 8;
            gll16(Bw + (n0 + row) * K + kt * 32 + col8, (char*)Bs[slot] + idx * 16);
        }
    };

    auto compute = [&](int slot, int stslot, int kstage) {
        const u16* Ab = As[slot];
        const u16* Bb = Bs[slot];
        short8 af[8], bfr[4];
        #pragma unroll
        for (int nf = 0; nf < 4; ++nf) {
            int row = wn * 64 + nf * 16 + lr;
            bfr[nf] = *(const short8*)((const char*)Bb + row * 64 +
                                       ((g ^ ((row >> 1) & 3)) << 4));
        }
        #pragma unroll
        for (int mf = 0; mf < 8; ++mf) {
            int row = wm * 128 + mf * 16 + lr;
            af[mf] = *(const short8*)((const char*)Ab + row * 64 +
                                      ((g ^ ((row >> 1) & 3)) << 4));
        }
        if (kstage >= 0) stage(stslot, kstage);   // re-stage slot(it-1)
        __builtin_amdgcn_s_setprio(1);
        #pragma unroll
        for (int mf = 0; mf < 8; ++mf)
            #pragma unroll
            for (int nf = 0; nf < 4; ++nf)
                acc[mf][nf] = __builtin_amdgcn_mfma_f32_16x16x32_bf16(
                    af[mf], bfr[nf], acc[mf][nf], 0, 0, 0);
        __builtin_amdgcn_s_setprio(0);
    };

    stage(0, 0);
    stage(1, 1);                    // 8 loads in flight
    int sl = 0;
    for (int it = 0; it + 2 < NT; ++it) {
        KWAIT(4);                   // tile it landed; it+1 still flying
        int s2 = sl + 2; if (s2 >= 3) s2 -= 3;
        compute(sl, s2, it + 2);
        ++sl; if (sl == 3) sl = 0;
    }
    KWAIT(4); compute(sl, 0, -1);   // tile NT-2 (NT-1 still flying)
    ++sl; if (sl == 3) sl = 0;
    KWAIT(0); compute(sl, 0, -1);   // tile NT-1

    // ---- fused RoPE epilogue (each wave spans exactly one 64-col head) ----
    if ((n0 + wn * 64) < 1536) {
        #pragma unroll
        for (int mf = 0; mf < 8; ++mf)
            #pragma unroll
            for (int r = 0; r < 4; ++r) {
                long row = m0 + wm * 128 + mf * 16 + g * 4 + r;
                const float2* tr = tab + row * 32;
                #pragma unroll
                for (int ntp = 0; ntp < 2; ++ntp) {
                    float2 cssn = tr[ntp * 16 + lr];
                    float x1 = acc[mf][ntp][r], x2 = acc[mf][ntp + 2][r];
                    acc[mf][ntp][r]     = x1 * cssn.x - x2 * cssn.y;
                    acc[mf][ntp + 2][r] = x2 * cssn.x + x1 * cssn.y;
                }
            }
    }

    #pragma unroll
    for (int mf = 0; mf < 8; ++mf)
        #pragma unroll
        for (int nf = 0; nf < 4; ++nf)
            #pragma unroll
            for (int r = 0; r < 4; ++r) {
                long row = m0 + wm * 128 + mf * 16 + g * 4 + r;
                long col = n0 + wn * 64 + nf * 16 + lr;
                C[row * N + col] = f2bf(acc[mf][nf][r]);
            }
}

// ---------------- bf16 GEMM (round-3 exact, for gemm2): C = A * B^T -------
template <int BM, int BN, typename OUT>
__global__ __launch_bounds__(256, 4) void gemm_bt(const u16* __restrict__ A,
                                                  const u16* __restrict__ Bw,
                                                  OUT* __restrict__ C,
                                                  int N, int K) {
    constexpr int WM = BM / 2, WN = BN / 2;
    constexpr int MR = WM / 16, NR = WN / 16;
    __shared__ __align__(16) u16 As[BM * 64];
    __shared__ __align__(16) u16 Bs[BN * 64];
    const int t = threadIdx.x;
    const int wid = t >> 6, lane = t & 63;
    const int wr = wid >> 1, wc = wid & 1;
    const long m0 = (long)blockIdx.x * BM;
    const long n0 = (long)blockIdx.y * BN;
    const int lr = lane & 15, g = lane >> 4;

    f32x4 acc[MR][NR] = {};

    for (int kt = 0; kt < K; kt += 64) {
        #pragma unroll
        for (int ss = 0; ss < BM / 32; ++ss) {
            int s = t + ss * 256;
            int row = s >> 3, gg = s & 7;
            int col8 = (gg ^ (row & 7)) * 8;
            gll16(A + (m0 + row) * K + kt + col8, (char*)As + s * 16);
        }
        #pragma unroll
        for (int ss = 0; ss < BN / 32; ++ss) {
            int s = t + ss * 256;
            int row = s >> 3, gg = s & 7;
            int col8 = (gg ^ (row & 7)) * 8;
            gll16(Bw + (n0 + row) * K + kt + col8, (char*)Bs + s * 16);
        }
        __syncthreads();
        #pragma unroll
        for (int kk2 = 0; kk2 < 2; ++kk2) {
            const int slot = kk2 * 4 + g;
            short8 bfr[NR];
            #pragma unroll
            for (int nt = 0; nt < NR; ++nt) {
                int row = wc * WN + nt * 16 + lr;
                bfr[nt] = *(const short8*)((const char*)Bs + row * 128 +
                                           ((slot ^ (row & 7)) << 4));
            }
            #pragma unroll
            for (int mt = 0; mt < MR; ++mt) {
                int row = wr * WM + mt * 16 + lr;
                short8 af = *(const short8*)((const char*)As + row * 128 +
                                             ((slot ^ (row & 7)) << 4));
                #pragma unroll
                for (int nt = 0; nt < NR; ++nt)
                    acc[mt][nt] = __builtin_amdgcn_mfma_f32_16x16x32_bf16(
                        af, bfr[nt], acc[mt][nt], 0, 0, 0);
            }
        }
        __syncthreads();
    }

    #pragma unroll
    for (int mt = 0; mt < MR; ++mt)
        #pragma unroll
        for (int nt = 0; nt < NR; ++nt)
            #pragma unroll
            for (int r = 0; r < 4; ++r) {
                long row = m0 + wr * WM + mt * 16 + g * 4 + r;
                long col = n0 + wc * WN + nt * 16 + lr;
                float v = acc[mt][nt][r];
                if constexpr (sizeof(OUT) == 2) C[row * N + col] = (OUT)f2bf(v);
                else                            C[row * N + col] = v;
            }
}

// ---------------- windowed attention ----------------
__global__ __launch_bounds__(256) void attn_k(const u16* __restrict__ qkv,
                                              u16* __restrict__ outb) {
    const int qt = blockIdx.x, bh = blockIdx.y;
    const int b = bh / NHn, h = bh % NHn;
    const int q0 = qt * 64, kv0 = q0 - 64;
    const int t = threadIdx.x, wid = t >> 6, lane = t & 63;
    const int lr = lane & 15, g = lane >> 4;

    __shared__ __align__(16) char smem[58368];
    u16* Qs = (u16*)smem;                // [64][64] swizzled, 8192 B
    u16* Ks = (u16*)(smem + 8192);       // [192][64] swizzled, 24576 B
    u16* Vt = (u16*)(smem + 32768);      // [64][200] transposed V, 25600 B

    const size_t rowbase = (size_t)b * Sn;

    #pragma unroll
    for (int ss = 0; ss < 2; ++ss) {
        int s = t + ss * 256;
        int row = s >> 3, gg = s & 7;
        int col8 = (gg ^ (row & 7)) * 8;
        gll16(qkv + (rowbase + q0 + row) * QKVN + h * 64 + col8, (char*)Qs + s * 16);
    }
    #pragma unroll
    for (int ss = 0; ss < 6; ++ss) {
        int s = t + ss * 256;
        int row = s >> 3, gg = s & 7;
        int kk = kv0 + row;
        kk = kk < 0 ? 0 : (kk > Sn - 1 ? Sn - 1 : kk);
        int col8 = (gg ^ (row & 7)) * 8;
        gll16(qkv + (rowbase + kk) * QKVN + 768 + h * 64 + col8, (char*)Ks + s * 16);
    }
    #pragma unroll
    for (int ss = 0; ss < 6; ++ss) {
        int s = t + ss * 256;
        int krow = s >> 3, gg = s & 7;
        int kk = kv0 + krow;
        kk = kk < 0 ? 0 : (kk > Sn - 1 ? Sn - 1 : kk);
        short8 v = *(const short8*)(qkv + (rowbase + kk) * QKVN + 1536 + h * 64 + gg * 8);
        #pragma unroll
        for (int j = 0; j < 8; ++j) Vt[(gg * 8 + j) * 200 + krow] = (u16)v[j];
    }
    __syncthreads();

    f32x4 sacc[12] = {};
    #pragma unroll
    for (int kk2 = 0; kk2 < 2; ++kk2) {
        int qrow = wid * 16 + lr;
        int slot = kk2 * 4 + g;
        short8 qf = *(const short8*)((const char*)Qs + qrow * 128 + ((slot ^ (qrow & 7)) << 4));
        #pragma unroll
        for (int tl = 0; tl < 12; ++tl) {
            int krow = tl * 16 + lr;
            short8 kf = *(const short8*)((const char*)Ks + krow * 128 + ((slot ^ (krow & 7)) << 4));
            sacc[tl] = __builtin_amdgcn_mfma_f32_16x16x32_bf16(qf, kf, sacc[tl], 0, 0, 0);
        }
    }

    float p[12][4];
    float lsum[4];
    #pragma unroll
    for (int r = 0; r < 4; ++r) {
        int qq = q0 + wid * 16 + g * 4 + r;
        float mx = -3.0e38f;
        #pragma unroll
        for (int tl = 0; tl < 12; ++tl) {
            int kq = kv0 + tl * 16 + lr;
            float sc = sacc[tl][r] * 0.125f;
            int dqk = qq - kq;
            bool valid = (kq >= 0) && (kq < Sn) && (dqk <= 64) && (dqk >= -64);
            sc = valid ? sc : -3.0e38f;
            p[tl][r] = sc;
            mx = fmaxf(mx, sc);
        }
        #pragma unroll
        for (int mk = 1; mk < 16; mk <<= 1) mx = fmaxf(mx, __shfl_xor(mx, mk, 16));
        float sum = 0.f;
        #pragma unroll
        for (int tl = 0; tl < 12; ++tl) {
            float e = __expf(p[tl][r] - mx);
            p[tl][r] = e;
            sum += e;
        }
        #pragma unroll
        for (int mk = 1; mk < 16; mk <<= 1) sum += __shfl_xor(sum, mk, 16);
        lsum[r] = sum;
    }

    __syncthreads();

    u16* Pw = (u16*)(smem + wid * 6400);
    #pragma unroll
    for (int tl = 0; tl < 12; ++tl)
        #pragma unroll
        for (int r = 0; r < 4; ++r)
            Pw[(g * 4 + r) * 200 + tl * 16 + lr] = f2bf(p[tl][r]);

    f32x4 oacc[4] = {};
    #pragma unroll
    for (int ks = 0; ks < 6; ++ks) {
        short8 pf = *(const short8*)((const char*)Pw + lr * 400 + (ks * 32 + g * 8) * 2);
        #pragma unroll
        for (int dt = 0; dt < 4; ++dt) {
            short8 vf = *(const short8*)((const char*)Vt + (dt * 16 + lr) * 400 + (ks * 32 + g * 8) * 2);
            oacc[dt] = __builtin_amdgcn_mfma_f32_16x16x32_bf16(pf, vf, oacc[dt], 0, 0, 0);
        }
    }

    #pragma unroll
    for (int dt = 0; dt < 4; ++dt)
        #pragma unroll
        for (int r = 0; r < 4; ++r) {
            int row = q0 + wid * 16 + g * 4 + r;
            float v = oacc[dt][r] / lsum[r];
            outb[(rowbase + row) * Hn + h * 64 + dt * 16 + lr] = f2bf(v);
        }
}

extern "C" void kernel_launch(void* const* d_in, const int* in_sizes, int n_in,
                              void* d_out, int out_size, void* d_ws, size_t ws_size,
                              hipStream_t stream) {
    const float* hs   = (const float*)d_in[0];
    const int*   pos  = (const int*)d_in[1];
    const float* wqkv = (const float*)d_in[2];
    const float* wo   = (const float*)d_in[3];
    float* out = (float*)d_out;
    char* ws = (char*)d_ws;

    u16* hs_b   = (u16*)(ws);              // 8192*768*2   = 12,582,912
    u16* wqkv_b = (u16*)(ws + 12582912);   // 2304*768*2   =  3,538,944
    u16* wo_b   = (u16*)(ws + 16121856);   // 768*768*2    =  1,179,648
    u16* qkv    = (u16*)(ws + 17301504);   // 8192*2304*2  = 37,748,736
    u16* attn   = (u16*)(ws + 55050240);   // 8192*768*2   = 12,582,912
    float2* tab = (float2*)(ws + 55050240);   // 2MB, dead before attn_k writes

    prep_k<<<9472, 256, 0, stream>>>(hs, wqkv, wo, pos, hs_b, wqkv_b, wo_b, tab);

    // qkv = hs @ Wqkv^T with fused RoPE (256^2 8-wave, high LDS intensity)
    gemm256<<<288, 512, 0, stream>>>(hs_b, wqkv_b, qkv, tab);

    attn_k<<<dim3(32, 48), 256, 0, stream>>>(qkv, attn);

    // out = attn @ Wo^T (fp32 out; round-3-exact kernel)
    gemm_bt<128, 64, float><<<dim3(64, 12), 256, 0, stream>>>(
        attn, wo_b, out, 768, 768);
}